// Round 5
// baseline (84.330 us; speedup 1.0000x reference)
//
#include <hip/hip_runtime.h>
#include <hip/hip_bf16.h>

#define OUT_CH 64
#define KSZ 7
#define STRIDE 2
#define PAD 3
#define HIDDEN 128
#define MAX_IN 3
#define B_SZ 32
#define H_IN 224
#define W_IN 224
#define H_OUT 112
#define W_OUT 112
#define WPB 147                       // 3*7*7 taps per (b,oc)
#define OUT_DIM (OUT_CH * WPB)        // 9408
#define SEGS 21                       // 3 channels * 7 kh rows
#define SEGP 24                       // padded segment count (6 MFMAs * 4)
#define WQ_PER_B (OUT_CH * SEGP * 8)  // 12288 bf16 per batch row
#define XRW 120                       // u32 per LDS x-row (240 bf16)

typedef __attribute__((ext_vector_type(8))) short short8;
typedef __attribute__((ext_vector_type(4))) float floatx4;

// ---------------- Kernel A: h = relu(mask @ W1 + b1) ----------------
__global__ void mlp1_kernel(const float* __restrict__ mask,
                            const float* __restrict__ W1,
                            const float* __restrict__ b1,
                            float* __restrict__ h) {
    int b = blockIdx.x;
    int j = threadIdx.x;
    float acc = b1[j];
#pragma unroll
    for (int c = 0; c < MAX_IN; ++c) {
        acc += mask[b * MAX_IN + c] * W1[c * HIDDEN + j];
    }
    h[b * HIDDEN + j] = fmaxf(acc, 0.0f);
}

// ---------------- Kernel B: weights -> padded bf16 A-operand layout ----------------
// wq[b][oc][seg(24)][t(8)] bf16; seg = c*7+kh (<21 real), t = kw (<7 real), pads = 0.
// grid(B_SZ, 48), block(256).
__global__ void mlp2_kernel(const float* __restrict__ h,
                            const float* __restrict__ W2,
                            const float* __restrict__ b2,
                            __hip_bfloat16* __restrict__ wq) {
    __shared__ float hs[HIDDEN];
    int b = blockIdx.x;
    int tid = threadIdx.x;
    if (tid < HIDDEN) hs[tid] = h[b * HIDDEN + tid];
    __syncthreads();
    int op = blockIdx.y * 256 + tid;          // 0..12287
    int oc  = op / (SEGP * 8);
    int rem = op - oc * (SEGP * 8);
    int seg = rem >> 3;
    int t   = rem & 7;
    float acc = 0.0f;
    if (seg < SEGS && t < 7) {
        int c  = seg / KSZ;
        int kh = seg - c * KSZ;
        int o = oc * WPB + c * 49 + kh * 7 + t;
        acc = b2[o];
#pragma unroll 8
        for (int j = 0; j < HIDDEN; ++j) {
            acc += hs[j] * W2[j * OUT_DIM + o];
        }
    }
    wq[(size_t)b * WQ_PER_B + op] = __float2bfloat16(acc);
}

// ---------------- Kernel C: grouped conv as implicit GEMM (MFMA) ----------------
// grid(112, 32), block(256) = 4 waves, block = one (b, oh).
// XCD-chunked: oh = (x&7)*14 + (x>>3), so XCD k owns oh in [14k,14k+14) for every b.
// Wave w handles pixel tiles {w, w+4} (wave 3: just {3}); each wave holds ALL 4
// oc-tiles' A-fragments so one B-fragment read feeds 4 MFMAs.
__global__ void __launch_bounds__(256, 2)
conv_kernel(const float* __restrict__ x,
            const __hip_bfloat16* __restrict__ wq,
            float* __restrict__ out) {
    __shared__ unsigned int xs[SEGS * XRW];   // 21 rows * 480 B = 10.1 KB

    const int xblk = blockIdx.x;
    const int oh = (xblk & 7) * 14 + (xblk >> 3);
    const int b  = blockIdx.y;
    const int tid = threadIdx.x;
    const int l  = tid & 63;
    const int w  = tid >> 6;
    const int lr = l & 15;              // A row (oc) / B,D col (pixel)
    const int lg = l >> 4;              // k-group / D row group

    // ---- A-fragments: all 4 oc-tiles x 6 MFMAs (issue first; overlaps staging) ----
    const unsigned short* wqb = (const unsigned short*)wq + (size_t)b * WQ_PER_B;
    short8 afr[4][6];
#pragma unroll
    for (int q = 0; q < 4; ++q)
#pragma unroll
        for (int mi = 0; mi < 6; ++mi)
            afr[q][mi] = *(const short8*)(wqb + ((size_t)(q * 16 + lr) * SEGP + 4 * mi + lg) * 8);

    // ---- stage x rows: f32 -> packed bf16, zero-padded halo ----
    const float* xbp = x + (size_t)b * MAX_IN * H_IN * W_IN;
    for (int i = tid; i < SEGS * XRW; i += 256) {
        int seg = i / XRW;
        int uw  = i - seg * XRW;
        int c   = seg / KSZ;
        int kh  = seg - c * KSZ;
        int ih  = oh * STRIDE + kh - PAD;
        int iw0 = uw * 2 - PAD;
        float f0 = 0.0f, f1 = 0.0f;
        if ((unsigned)ih < (unsigned)H_IN) {
            const float* xr = xbp + ((size_t)c * H_IN + ih) * W_IN;
            if ((unsigned)iw0 < (unsigned)W_IN)       f0 = xr[iw0];
            if ((unsigned)(iw0 + 1) < (unsigned)W_IN) f1 = xr[iw0 + 1];
        }
        unsigned int lo = __bfloat16_as_ushort(__float2bfloat16(f0));
        unsigned int hi = __bfloat16_as_ushort(__float2bfloat16(f1));
        xs[i] = lo | (hi << 16);
    }
    __syncthreads();

    // per-lane B row index for each mi (seg = 4mi+lg)
    int rowidx[6];
#pragma unroll
    for (int mi = 0; mi < 6; ++mi) {
        int seg = 4 * mi + lg;
        if (seg >= SEGS) seg = 0;       // padded k: A weights are 0 there
        rowidx[mi] = seg * XRW;
    }

#pragma unroll
    for (int tt = 0; tt < 2; ++tt) {
        const int t = w + 4 * tt;       // tiles {w, w+4}; wave 3 skips second
        if (t > 6) break;
        const int ow = t * 16 + lr;

        union { short8 s; unsigned int u[4]; } bu[6];
#pragma unroll
        for (int mi = 0; mi < 6; ++mi) {
            const unsigned int* xr = xs + rowidx[mi] + ow;
            bu[mi].u[0] = xr[0];
            bu[mi].u[1] = xr[1];
            bu[mi].u[2] = xr[2];
            bu[mi].u[3] = xr[3];
        }

        floatx4 acc[4];
#pragma unroll
        for (int q = 0; q < 4; ++q) acc[q] = (floatx4){0.0f, 0.0f, 0.0f, 0.0f};
#pragma unroll
        for (int mi = 0; mi < 6; ++mi)
#pragma unroll
            for (int q = 0; q < 4; ++q)
                acc[q] = __builtin_amdgcn_mfma_f32_16x16x32_bf16(afr[q][mi], bu[mi].s, acc[q], 0, 0, 0);

#pragma unroll
        for (int q = 0; q < 4; ++q) {
            float* op = out + (((size_t)b * OUT_CH + q * 16 + lg * 4) * H_OUT + oh) * W_OUT + ow;
#pragma unroll
            for (int r = 0; r < 4; ++r)
                op[(size_t)r * H_OUT * W_OUT] = acc[q][r];
        }
    }
}

extern "C" void kernel_launch(void* const* d_in, const int* in_sizes, int n_in,
                              void* d_out, int out_size, void* d_ws, size_t ws_size,
                              hipStream_t stream) {
    const float* x    = (const float*)d_in[0];   // [32,3,224,224]
    const float* mask = (const float*)d_in[1];   // [32,3]
    const float* W1   = (const float*)d_in[2];   // [3,128]
    const float* b1   = (const float*)d_in[3];   // [128]
    const float* W2   = (const float*)d_in[4];   // [128,9408]
    const float* b2   = (const float*)d_in[5];   // [9408]
    float* out = (float*)d_out;

    float* h = (float*)d_ws;                                     // 16 KB
    __hip_bfloat16* wq = (__hip_bfloat16*)((char*)d_ws + 16384); // 768 KB

    mlp1_kernel<<<dim3(B_SZ), dim3(HIDDEN), 0, stream>>>(mask, W1, b1, h);
    mlp2_kernel<<<dim3(B_SZ, 48), dim3(256), 0, stream>>>(h, W2, b2, wq);
    conv_kernel<<<dim3(112, B_SZ), dim3(256), 0, stream>>>(x, wq, out);
}

// Round 6
// 61.399 us; speedup vs baseline: 1.3735x; 1.3735x over previous
//
#include <hip/hip_runtime.h>
#include <hip/hip_bf16.h>

#define OUT_CH 64
#define KSZ 7
#define STRIDE 2
#define PAD 3
#define HIDDEN 128
#define MAX_IN 3
#define B_SZ 32
#define H_IN 224
#define W_IN 224
#define H_OUT 112
#define W_OUT 112
#define WPB 147                       // 3*7*7 taps per (b,oc)
#define OUT_DIM (OUT_CH * WPB)        // 9408
#define SEGS 21                       // 3 channels * 7 kh rows
#define SEGP 24                       // padded segment count (6 MFMAs * 4)
#define WQ_PER_B (OUT_CH * SEGP * 8)  // 12288 bf16 per batch row
#define XRW 120                       // u32 per LDS x-row (240 bf16)
#define NSLOT (SEGS * XRW)            // 2520 u32 per oh-row stage
#define OH_PER_BLK 7                  // oh rows per conv block

typedef __attribute__((ext_vector_type(8))) short short8;
typedef __attribute__((ext_vector_type(4))) float floatx4;

// ---------------- Kernel A: h = relu(mask @ W1 + b1) ----------------
__global__ void mlp1_kernel(const float* __restrict__ mask,
                            const float* __restrict__ W1,
                            const float* __restrict__ b1,
                            float* __restrict__ h) {
    int b = blockIdx.x;
    int j = threadIdx.x;
    float acc = b1[j];
#pragma unroll
    for (int c = 0; c < MAX_IN; ++c) {
        acc += mask[b * MAX_IN + c] * W1[c * HIDDEN + j];
    }
    h[b * HIDDEN + j] = fmaxf(acc, 0.0f);
}

// ---------------- Kernel B: weights -> padded bf16 A-operand layout ----------------
// 4 batch rows per block (W2 reuse): grid(8, 48), block(256).
// wq[b][oc][seg(24)][t(8)] bf16; seg = c*7+kh (<21 real), t = kw (<7 real), pads = 0.
__global__ void mlp2_kernel(const float* __restrict__ h,
                            const float* __restrict__ W2,
                            const float* __restrict__ b2,
                            __hip_bfloat16* __restrict__ wq) {
    __shared__ float hs[4][HIDDEN];
    const int tid = threadIdx.x;
    const int b0 = blockIdx.x * 4;
    for (int i = tid; i < 4 * HIDDEN; i += 256)
        hs[i >> 7][i & (HIDDEN - 1)] = h[(b0 + (i >> 7)) * HIDDEN + (i & (HIDDEN - 1))];
    __syncthreads();

    const int op = blockIdx.y * 256 + tid;    // 0..12287
    const int oc  = op / (SEGP * 8);
    const int rem = op - oc * (SEGP * 8);
    const int seg = rem >> 3;
    const int t   = rem & 7;

    float acc[4] = {0.0f, 0.0f, 0.0f, 0.0f};
    if (seg < SEGS && t < 7) {
        int c  = seg / KSZ;
        int kh = seg - c * KSZ;
        int o  = oc * WPB + c * 49 + kh * 7 + t;
        float bias = b2[o];
#pragma unroll
        for (int q = 0; q < 4; ++q) acc[q] = bias;
        const float* w2p = W2 + o;
#pragma unroll 8
        for (int j = 0; j < HIDDEN; ++j) {
            float w = w2p[(size_t)j * OUT_DIM];
#pragma unroll
            for (int q = 0; q < 4; ++q) acc[q] += hs[q][j] * w;
        }
    }
#pragma unroll
    for (int q = 0; q < 4; ++q)
        wq[(size_t)(b0 + q) * WQ_PER_B + op] = __float2bfloat16(acc[q]);
}

// ---------------- conv helpers: split staging (issue-early / write-late) ----------------
__device__ __forceinline__ void stage_issue(const float* __restrict__ xbp, int oh, int tid,
                                            float* f0, float* f1) {
#pragma unroll
    for (int s = 0; s < 10; ++s) {
        int i = tid + 256 * s;
        float a = 0.0f, bb = 0.0f;
        if (i < NSLOT) {
            int seg = i / XRW;
            int uw  = i - seg * XRW;
            int c   = seg / KSZ;
            int kh  = seg - c * KSZ;
            int ih  = oh * STRIDE + kh - PAD;
            int iw0 = uw * 2 - PAD;
            if ((unsigned)ih < (unsigned)H_IN) {
                const float* xr = xbp + ((size_t)c * H_IN + ih) * W_IN;
                if ((unsigned)iw0 < (unsigned)W_IN)       a  = xr[iw0];
                if ((unsigned)(iw0 + 1) < (unsigned)W_IN) bb = xr[iw0 + 1];
            }
        }
        f0[s] = a;
        f1[s] = bb;
    }
}

__device__ __forceinline__ void stage_write(unsigned int* __restrict__ buf, int tid,
                                            const float* f0, const float* f1) {
#pragma unroll
    for (int s = 0; s < 10; ++s) {
        int i = tid + 256 * s;
        if (i < NSLOT) {
            unsigned int lo = __bfloat16_as_ushort(__float2bfloat16(f0[s]));
            unsigned int hi = __bfloat16_as_ushort(__float2bfloat16(f1[s]));
            buf[i] = lo | (hi << 16);
        }
    }
}

// ---------------- Kernel C: grouped conv as implicit GEMM (MFMA) ----------------
// grid(16, 32), block(256) = 4 waves. Block: (b, oh band of 7). Wave w = oc-tile w.
// Double-buffered LDS, software-pipelined over oh: issue loads(oh+1) -> compute(oh)
// -> convert+write(oh+1) -> barrier. One barrier per oh.
__global__ void __launch_bounds__(256, 2)
conv_kernel(const float* __restrict__ x,
            const __hip_bfloat16* __restrict__ wq,
            float* __restrict__ out) {
    __shared__ unsigned int xs[2][NSLOT];     // 2 * 10.08 KB

    const int oh0 = blockIdx.x * OH_PER_BLK;
    const int b   = blockIdx.y;
    const int tid = threadIdx.x;
    const int w   = tid >> 6;           // wave -> oc-tile
    const int l   = tid & 63;
    const int lr  = l & 15;             // A row (oc) / B,D col (pixel)
    const int lg  = l >> 4;             // k-group / D row group

    // ---- A-fragments: this wave's oc-tile, 6 MFMAs; loaded once per block ----
    const unsigned short* wqb = (const unsigned short*)wq
        + ((size_t)b * OUT_CH + w * 16 + lr) * (SEGP * 8);
    short8 afr[6];
#pragma unroll
    for (int mi = 0; mi < 6; ++mi)
        afr[mi] = *(const short8*)(wqb + (4 * mi + lg) * 8);

    // per-lane B row index for each mi (seg = 4mi+lg)
    int rowidx[6];
#pragma unroll
    for (int mi = 0; mi < 6; ++mi) {
        int seg = 4 * mi + lg;
        if (seg >= SEGS) seg = 0;       // padded k: A weights are 0 there
        rowidx[mi] = seg * XRW;
    }

    const float* xbp = x + (size_t)b * MAX_IN * H_IN * W_IN;

    float f0[10], f1[10];
    stage_issue(xbp, oh0, tid, f0, f1);
    stage_write(xs[0], tid, f0, f1);
    __syncthreads();

    int cur = 0;
    for (int i = 0; i < OH_PER_BLK; ++i) {
        const int oh = oh0 + i;
        if (i < OH_PER_BLK - 1)
            stage_issue(xbp, oh + 1, tid, f0, f1);   // HBM latency hides under compute

        const unsigned int* xc = xs[cur];
#pragma unroll
        for (int t = 0; t < 7; ++t) {
            const int ow = t * 16 + lr;
            union { short8 s; unsigned int u[4]; } bu[6];
#pragma unroll
            for (int mi = 0; mi < 6; ++mi) {
                const unsigned int* xr = xc + rowidx[mi] + ow;
                bu[mi].u[0] = xr[0];
                bu[mi].u[1] = xr[1];
                bu[mi].u[2] = xr[2];
                bu[mi].u[3] = xr[3];
            }
            floatx4 acc = {0.0f, 0.0f, 0.0f, 0.0f};
#pragma unroll
            for (int mi = 0; mi < 6; ++mi)
                acc = __builtin_amdgcn_mfma_f32_16x16x32_bf16(afr[mi], bu[mi].s, acc, 0, 0, 0);

            float* op = out + (((size_t)b * OUT_CH + w * 16 + lg * 4) * H_OUT + oh) * W_OUT + ow;
#pragma unroll
            for (int r = 0; r < 4; ++r)
                op[(size_t)r * H_OUT * W_OUT] = acc[r];
        }

        if (i < OH_PER_BLK - 1) {
            stage_write(xs[cur ^ 1], tid, f0, f1);
            __syncthreads();
            cur ^= 1;
        }
    }
}

extern "C" void kernel_launch(void* const* d_in, const int* in_sizes, int n_in,
                              void* d_out, int out_size, void* d_ws, size_t ws_size,
                              hipStream_t stream) {
    const float* x    = (const float*)d_in[0];   // [32,3,224,224]
    const float* mask = (const float*)d_in[1];   // [32,3]
    const float* W1   = (const float*)d_in[2];   // [3,128]
    const float* b1   = (const float*)d_in[3];   // [128]
    const float* W2   = (const float*)d_in[4];   // [128,9408]
    const float* b2   = (const float*)d_in[5];   // [9408]
    float* out = (float*)d_out;

    float* h = (float*)d_ws;                                     // 16 KB
    __hip_bfloat16* wq = (__hip_bfloat16*)((char*)d_ws + 16384); // 768 KB

    mlp1_kernel<<<dim3(B_SZ), dim3(HIDDEN), 0, stream>>>(mask, W1, b1, h);
    mlp2_kernel<<<dim3(8, 48), dim3(256), 0, stream>>>(h, W2, b2, wq);
    conv_kernel<<<dim3(16, B_SZ), dim3(256), 0, stream>>>(x, wq, out);
}

// Round 7
// 51.264 us; speedup vs baseline: 1.6450x; 1.1977x over previous
//
#include <hip/hip_runtime.h>
#include <hip/hip_bf16.h>

#define OUT_CH 64
#define KSZ 7
#define STRIDE 2
#define PAD 3
#define HIDDEN 128
#define MAX_IN 3
#define B_SZ 32
#define H_IN 224
#define W_IN 224
#define H_OUT 112
#define W_OUT 112
#define WPB 147                       // 3*7*7 taps per (b,oc)
#define OUT_DIM (OUT_CH * WPB)        // 9408
#define SEGS 21                       // 3 channels * 7 kh rows
#define SEGP 24                       // padded segment count (6 MFMAs * 4)
#define WQ_PER_B (OUT_CH * SEGP * 8)  // 12288 bf16 per batch row
#define XRW 120                       // u32 per LDS x-row (240 bf16)
#define NSLOT (SEGS * XRW)            // 2520 u32 staged per (b,oh)

typedef __attribute__((ext_vector_type(8))) short short8;
typedef __attribute__((ext_vector_type(4))) float floatx4;

// ---------------- Kernel A: fused weight generator ----------------
// grid(8, 48), block(256). Recomputes h = relu(mask@W1+b1) for its 4 b's (cheap),
// then writes wq[b][oc][mi][lg][e] bf16 in the conv A-fragment order:
//   seg = 4*mi + (e>>1)  (c*7+kh, <21 real),  tap = 2*lg + (e&1)  (kw, <7 real)
// Pad slots are 0 so padded k contributes nothing.
__global__ void wgen_kernel(const float* __restrict__ mask,
                            const float* __restrict__ W1,
                            const float* __restrict__ b1,
                            const float* __restrict__ W2,
                            const float* __restrict__ b2,
                            __hip_bfloat16* __restrict__ wq) {
    __shared__ float hs[4][HIDDEN];
    const int tid = threadIdx.x;
    const int b0 = blockIdx.x * 4;

    for (int i = tid; i < 4 * HIDDEN; i += 256) {
        int q = i >> 7;
        int j = i & (HIDDEN - 1);
        float a = b1[j];
#pragma unroll
        for (int c = 0; c < MAX_IN; ++c)
            a += mask[(b0 + q) * MAX_IN + c] * W1[c * HIDDEN + j];
        hs[q][j] = fmaxf(a, 0.0f);
    }
    __syncthreads();

    const int op = blockIdx.y * 256 + tid;    // 0..12287
    const int oc  = op / 192;
    const int r   = op - oc * 192;            // [mi][lg][e]
    const int mi  = r >> 5;
    const int lg  = (r >> 3) & 3;
    const int e   = r & 7;
    const int seg = 4 * mi + (e >> 1);
    const int tap = 2 * lg + (e & 1);

    float acc[4] = {0.0f, 0.0f, 0.0f, 0.0f};
    if (seg < SEGS && tap < KSZ) {
        int o = oc * WPB + seg * KSZ + tap;
        float bias = b2[o];
#pragma unroll
        for (int q = 0; q < 4; ++q) acc[q] = bias;
        const float* w2p = W2 + o;
#pragma unroll 8
        for (int j = 0; j < HIDDEN; ++j) {
            float w = w2p[(size_t)j * OUT_DIM];
#pragma unroll
            for (int q = 0; q < 4; ++q) acc[q] += hs[q][j] * w;
        }
    }
#pragma unroll
    for (int q = 0; q < 4; ++q)
        wq[(size_t)(b0 + q) * WQ_PER_B + op] = __float2bfloat16(acc[q]);
}

// ---------------- Kernel B: grouped conv as implicit GEMM (MFMA) ----------------
// grid(112, 32), block(256) = 4 waves; block = one (b, oh); wave w = oc-tile w.
// XCD-chunked: oh = (x&7)*14 + (x>>3)  (XCD k owns a contiguous 14-row oh band).
// B-fragment: 4 separate b32 LDS reads from 4 different rows (un-mergeable,
// broadcast-coalesced, conflict-free). k-mapping matches wgen above.
__global__ void __launch_bounds__(256, 4)
conv_kernel(const float* __restrict__ x,
            const __hip_bfloat16* __restrict__ wq,
            float* __restrict__ out) {
    __shared__ unsigned int xs[NSLOT];        // 21 rows * 480 B = 10.08 KB

    const int xblk = blockIdx.x;
    const int oh = (xblk & 7) * 14 + (xblk >> 3);
    const int b  = blockIdx.y;
    const int tid = threadIdx.x;
    const int w  = tid >> 6;            // wave -> oc-tile
    const int l  = tid & 63;
    const int lr = l & 15;              // A row (oc) / B,D col (pixel)
    const int lg = l >> 4;              // k-group / D row group

    // ---- A-fragments (this wave's oc-tile), coalesced 16B loads from L2-hot wq ----
    const unsigned short* wqb = (const unsigned short*)wq
        + ((size_t)b * OUT_CH + w * 16 + lr) * (SEGP * 8);
    short8 afr[6];
#pragma unroll
    for (int mi = 0; mi < 6; ++mi)
        afr[mi] = *(const short8*)(wqb + mi * 32 + lg * 8);

    // ---- stage x rows: f32 -> packed bf16, zero-padded halo ----
    const float* xbp = x + (size_t)b * MAX_IN * H_IN * W_IN;
    for (int i = tid; i < NSLOT; i += 256) {
        int seg = i / XRW;
        int uw  = i - seg * XRW;
        int c   = seg / KSZ;
        int kh  = seg - c * KSZ;
        int ih  = oh * STRIDE + kh - PAD;
        int iw0 = uw * 2 - PAD;
        float f0 = 0.0f, f1 = 0.0f;
        if ((unsigned)ih < (unsigned)H_IN) {
            const float* xr = xbp + ((size_t)c * H_IN + ih) * W_IN;
            if ((unsigned)iw0 < (unsigned)W_IN)       f0 = xr[iw0];
            if ((unsigned)(iw0 + 1) < (unsigned)W_IN) f1 = xr[iw0 + 1];
        }
        unsigned int lo = __bfloat16_as_ushort(__float2bfloat16(f0));
        unsigned int hi = __bfloat16_as_ushort(__float2bfloat16(f1));
        xs[i] = lo | (hi << 16);
    }
    __syncthreads();

    const int abase = lr + lg;          // per-lane address offset within a row

#pragma unroll
    for (int t = 0; t < 7; ++t) {
        const int tb = t * 16 + abase;
        floatx4 acc = {0.0f, 0.0f, 0.0f, 0.0f};
#pragma unroll
        for (int mi = 0; mi < 6; ++mi) {
            union { short8 s; unsigned int u[4]; } bu;
#pragma unroll
            for (int s = 0; s < 4; ++s) {
                const int seg = 4 * mi + s;                 // compile-time
                const int rb  = (seg < SEGS ? seg : 0) * XRW;
                bu.u[s] = xs[rb + tb];
            }
            acc = __builtin_amdgcn_mfma_f32_16x16x32_bf16(afr[mi], bu.s, acc, 0, 0, 0);
        }
        const int ow = t * 16 + lr;
        float* op = out + (((size_t)b * OUT_CH + w * 16 + lg * 4) * H_OUT + oh) * W_OUT + ow;
#pragma unroll
        for (int r = 0; r < 4; ++r)
            op[(size_t)r * H_OUT * W_OUT] = acc[r];
    }
}

extern "C" void kernel_launch(void* const* d_in, const int* in_sizes, int n_in,
                              void* d_out, int out_size, void* d_ws, size_t ws_size,
                              hipStream_t stream) {
    const float* x    = (const float*)d_in[0];   // [32,3,224,224]
    const float* mask = (const float*)d_in[1];   // [32,3]
    const float* W1   = (const float*)d_in[2];   // [3,128]
    const float* b1   = (const float*)d_in[3];   // [128]
    const float* W2   = (const float*)d_in[4];   // [128,9408]
    const float* b2   = (const float*)d_in[5];   // [9408]
    float* out = (float*)d_out;

    __hip_bfloat16* wq = (__hip_bfloat16*)d_ws;  // 32*12288*2 = 768 KB

    wgen_kernel<<<dim3(8, 48), dim3(256), 0, stream>>>(mask, W1, b1, W2, b2, wq);
    conv_kernel<<<dim3(112, B_SZ), dim3(256), 0, stream>>>(x, wq, out);
}

// Round 8
// 50.011 us; speedup vs baseline: 1.6862x; 1.0250x over previous
//
#include <hip/hip_runtime.h>
#include <hip/hip_bf16.h>

#define OUT_CH 64
#define KSZ 7
#define STRIDE 2
#define PAD 3
#define HIDDEN 128
#define MAX_IN 3
#define B_SZ 32
#define H_IN 224
#define W_IN 224
#define H_OUT 112
#define W_OUT 112
#define WPB 147                       // 3*7*7 taps per (b,oc)
#define OUT_DIM (OUT_CH * WPB)        // 9408
#define SEGS 21                       // 3 channels * 7 kh rows
#define SEGP 24                       // padded segment count (6 MFMAs * 4)
#define WQ_PER_B (OUT_CH * SEGP * 8)  // 12288 bf16 per batch row
#define XRW 120                       // u32 per LDS x-row (240 bf16)
#define NSLOT (SEGS * XRW)            // 2520 u32 staged per (b,oh)
#define NPAIR (NSLOT / 2)             // 1260 u64 pairs

typedef __attribute__((ext_vector_type(8))) short short8;
typedef __attribute__((ext_vector_type(4))) float floatx4;

// ---------------- Kernel A: fused weight generator ----------------
// grid(8, 48), block(256). Recomputes h = relu(mask@W1+b1) for its 4 b's,
// writes wq[b][oc][mi][lg][e] bf16 in the conv A-fragment order:
//   seg = 4*mi + 2*(lg>>1) + (e>>2)   (c*7+kh, <21 real)
//   tap = 4*(lg&1) + (e&3)            (kw, <7 real)
// Pad slots are 0 so padded k contributes nothing.
__global__ void wgen_kernel(const float* __restrict__ mask,
                            const float* __restrict__ W1,
                            const float* __restrict__ b1,
                            const float* __restrict__ W2,
                            const float* __restrict__ b2,
                            __hip_bfloat16* __restrict__ wq) {
    __shared__ float hs[4][HIDDEN];
    const int tid = threadIdx.x;
    const int b0 = blockIdx.x * 4;

    for (int i = tid; i < 4 * HIDDEN; i += 256) {
        int q = i >> 7;
        int j = i & (HIDDEN - 1);
        float a = b1[j];
#pragma unroll
        for (int c = 0; c < MAX_IN; ++c)
            a += mask[(b0 + q) * MAX_IN + c] * W1[c * HIDDEN + j];
        hs[q][j] = fmaxf(a, 0.0f);
    }
    __syncthreads();

    const int op = blockIdx.y * 256 + tid;    // 0..12287
    const int oc  = op / 192;
    const int r   = op - oc * 192;            // [mi][lg][e]
    const int mi  = r >> 5;
    const int lg  = (r >> 3) & 3;
    const int e   = r & 7;
    const int seg = 4 * mi + 2 * (lg >> 1) + (e >> 2);
    const int tap = 4 * (lg & 1) + (e & 3);

    float acc[4] = {0.0f, 0.0f, 0.0f, 0.0f};
    if (seg < SEGS && tap < KSZ) {
        int o = oc * WPB + seg * KSZ + tap;
        float bias = b2[o];
#pragma unroll
        for (int q = 0; q < 4; ++q) acc[q] = bias;
        const float* w2p = W2 + o;
#pragma unroll 8
        for (int j = 0; j < HIDDEN; ++j) {
            float w = w2p[(size_t)j * OUT_DIM];
#pragma unroll
            for (int q = 0; q < 4; ++q) acc[q] += hs[q][j] * w;
        }
    }
#pragma unroll
    for (int q = 0; q < 4; ++q)
        wq[(size_t)(b0 + q) * WQ_PER_B + op] = __float2bfloat16(acc[q]);
}

// ---------------- Kernel B: grouped conv as implicit GEMM (MFMA) ----------------
// grid(112, 32), block(256) = 4 waves; block = one (b, oh); wave w = oc-tile w.
// XCD-chunked: oh = (x&7)*14 + (x>>3).
// B-fragment per mi: 2 rows x 2 adjacent u32 -> paired LDS reads (ds_read2_b32),
// <=2-way bank aliasing (free). k-map matches wgen above.
__global__ void __launch_bounds__(256, 6)
conv_kernel(const float* __restrict__ x,
            const __hip_bfloat16* __restrict__ wq,
            float* __restrict__ out) {
    __shared__ unsigned int xs[NSLOT];        // 21 rows * 480 B = 10.08 KB

    const int xblk = blockIdx.x;
    const int oh = (xblk & 7) * 14 + (xblk >> 3);
    const int b  = blockIdx.y;
    const int tid = threadIdx.x;
    const int w  = tid >> 6;            // wave -> oc-tile
    const int l  = tid & 63;
    const int lr = l & 15;              // A row (oc) / B,D col (pixel)
    const int lg = l >> 4;              // k-group / D row group

    // ---- A-fragments (this wave's oc-tile), coalesced 16B loads from L2-hot wq ----
    const unsigned short* wqb = (const unsigned short*)wq
        + ((size_t)b * OUT_CH + w * 16 + lr) * (SEGP * 8);
    short8 afr[6];
#pragma unroll
    for (int mi = 0; mi < 6; ++mi)
        afr[mi] = *(const short8*)(wqb + mi * 32 + lg * 8);

    // ---- stage x rows: f32 -> packed bf16 pairs, zero-padded halo ----
    const float* xbp = x + (size_t)b * MAX_IN * H_IN * W_IN;
#pragma unroll
    for (int s = 0; s < 5; ++s) {
        int p = tid + 256 * s;
        if (p < NPAIR) {
            int row = p / 60;              // c*7 + kh
            int pu  = p - row * 60;        // pair index within row
            int c   = row / KSZ;
            int kh  = row - c * KSZ;
            int ih  = oh * STRIDE + kh - PAD;
            int iw0 = 4 * pu - PAD;
            float f0 = 0.0f, f1 = 0.0f, f2 = 0.0f, f3 = 0.0f;
            if ((unsigned)ih < (unsigned)H_IN) {
                const float* xr = xbp + ((size_t)c * H_IN + ih) * W_IN;
                if (iw0 >= 0 && iw0 <= W_IN - 4) {
                    f0 = xr[iw0]; f1 = xr[iw0 + 1]; f2 = xr[iw0 + 2]; f3 = xr[iw0 + 3];
                } else {
                    if ((unsigned)iw0 < (unsigned)W_IN)       f0 = xr[iw0];
                    if ((unsigned)(iw0 + 1) < (unsigned)W_IN) f1 = xr[iw0 + 1];
                    if ((unsigned)(iw0 + 2) < (unsigned)W_IN) f2 = xr[iw0 + 2];
                    if ((unsigned)(iw0 + 3) < (unsigned)W_IN) f3 = xr[iw0 + 3];
                }
            }
            unsigned long long lo = __bfloat16_as_ushort(__float2bfloat16(f0))
                                  | ((unsigned int)__bfloat16_as_ushort(__float2bfloat16(f1)) << 16);
            unsigned long long hi = __bfloat16_as_ushort(__float2bfloat16(f2))
                                  | ((unsigned int)__bfloat16_as_ushort(__float2bfloat16(f3)) << 16);
            *(unsigned long long*)&xs[row * XRW + 2 * pu] = lo | (hi << 32);
        }
    }
    __syncthreads();

    // ---- per-lane LDS u32 index bases: 2 rows per mi, col = lr + 2*(lg&1) ----
    const int col = lr + 2 * (lg & 1);
    int ra[6], rb[6];
#pragma unroll
    for (int mi = 0; mi < 6; ++mi) {
        int sa = 4 * mi + 2 * (lg >> 1);
        int sb = sa + 1;
        ra[mi] = (sa < SEGS ? sa : 0) * XRW + col;   // clamped rows pair with 0-weights
        rb[mi] = (sb < SEGS ? sb : 0) * XRW + col;
    }

#pragma unroll
    for (int t = 0; t < 7; ++t) {
        const int tb = t * 16;
        floatx4 acc = {0.0f, 0.0f, 0.0f, 0.0f};
#pragma unroll
        for (int mi = 0; mi < 6; ++mi) {
            union { short8 s; unsigned int u[4]; } bu;
            const unsigned int* pa = xs + ra[mi] + tb;
            const unsigned int* pb = xs + rb[mi] + tb;
            bu.u[0] = pa[0];
            bu.u[1] = pa[1];
            bu.u[2] = pb[0];
            bu.u[3] = pb[1];
            acc = __builtin_amdgcn_mfma_f32_16x16x32_bf16(afr[mi], bu.s, acc, 0, 0, 0);
        }
        const int ow = tb + lr;
        float* op = out + (((size_t)b * OUT_CH + w * 16 + lg * 4) * H_OUT + oh) * W_OUT + ow;
#pragma unroll
        for (int r = 0; r < 4; ++r)
            op[(size_t)r * H_OUT * W_OUT] = acc[r];
    }
}

extern "C" void kernel_launch(void* const* d_in, const int* in_sizes, int n_in,
                              void* d_out, int out_size, void* d_ws, size_t ws_size,
                              hipStream_t stream) {
    const float* x    = (const float*)d_in[0];   // [32,3,224,224]
    const float* mask = (const float*)d_in[1];   // [32,3]
    const float* W1   = (const float*)d_in[2];   // [3,128]
    const float* b1   = (const float*)d_in[3];   // [128]
    const float* W2   = (const float*)d_in[4];   // [128,9408]
    const float* b2   = (const float*)d_in[5];   // [9408]
    float* out = (float*)d_out;

    __hip_bfloat16* wq = (__hip_bfloat16*)d_ws;  // 32*12288*2 = 768 KB

    wgen_kernel<<<dim3(8, 48), dim3(256), 0, stream>>>(mask, W1, b1, W2, b2, wq);
    conv_kernel<<<dim3(112, B_SZ), dim3(256), 0, stream>>>(x, wq, out);
}

// Round 9
// 45.024 us; speedup vs baseline: 1.8730x; 1.1108x over previous
//
#include <hip/hip_runtime.h>
#include <hip/hip_bf16.h>

#define OUT_CH 64
#define KSZ 7
#define STRIDE 2
#define PAD 3
#define HIDDEN 128
#define MAX_IN 3
#define B_SZ 32
#define H_IN 224
#define W_IN 224
#define H_OUT 112
#define W_OUT 112
#define WPB 147                       // 3*7*7 taps per (b,oc)
#define OUT_DIM (OUT_CH * WPB)        // 9408
#define SEGS 21                       // 3 channels * 7 kh rows
#define SEGP 24                       // padded segment count (6 MFMAs * 4)
#define WQ_PER_B (OUT_CH * SEGP * 8)  // 12288 bf16 per batch row
#define XRW 120                       // u32 per x row (240 bf16, iw = j-3)
#define XSROWS 24                     // LDS rows (21 real + 3 scratch)

typedef __attribute__((ext_vector_type(8))) short short8;
typedef __attribute__((ext_vector_type(4))) float floatx4;

// ---------------- Kernel 0: x f32 -> padded bf16 rows ----------------
// xbf[(b*3+c)*224 + ih][uw] u32 = bf16 pair (iw=2uw-3, iw=2uw-2), zero-padded.
// Also zeroes the 480B zpad row (block 0).
__global__ void xprep_kernel(const float* __restrict__ x,
                             unsigned int* __restrict__ xbf,
                             unsigned int* __restrict__ zpad) {
    int s = blockIdx.x * 256 + threadIdx.x;       // 0 .. 32*3*224*120-1 (exact grid)
    int r = s / XRW;
    int uw = s - r * XRW;
    const float* xr = x + (size_t)r * W_IN;
    int iw0 = 2 * uw - 3;
    float f0 = ((unsigned)iw0 < (unsigned)W_IN) ? xr[iw0] : 0.0f;
    float f1 = ((unsigned)(iw0 + 1) < (unsigned)W_IN) ? xr[iw0 + 1] : 0.0f;
    unsigned int lo = __bfloat16_as_ushort(__float2bfloat16(f0));
    unsigned int hi = __bfloat16_as_ushort(__float2bfloat16(f1));
    xbf[s] = lo | (hi << 16);
    if (blockIdx.x == 0 && threadIdx.x < XRW) zpad[threadIdx.x] = 0;
}

// ---------------- Kernel 1: fused weight generator (unchanged from R8) ----------------
// wq[b][oc][mi][lg][e] bf16:  seg = 4*mi + 2*(lg>>1) + (e>>2), tap = 4*(lg&1) + (e&3)
__global__ void wgen_kernel(const float* __restrict__ mask,
                            const float* __restrict__ W1,
                            const float* __restrict__ b1,
                            const float* __restrict__ W2,
                            const float* __restrict__ b2,
                            __hip_bfloat16* __restrict__ wq) {
    __shared__ float hs[4][HIDDEN];
    const int tid = threadIdx.x;
    const int b0 = blockIdx.x * 4;

    for (int i = tid; i < 4 * HIDDEN; i += 256) {
        int q = i >> 7;
        int j = i & (HIDDEN - 1);
        float a = b1[j];
#pragma unroll
        for (int c = 0; c < MAX_IN; ++c)
            a += mask[(b0 + q) * MAX_IN + c] * W1[c * HIDDEN + j];
        hs[q][j] = fmaxf(a, 0.0f);
    }
    __syncthreads();

    const int op = blockIdx.y * 256 + tid;    // 0..12287
    const int oc  = op / 192;
    const int r   = op - oc * 192;            // [mi][lg][e]
    const int mi  = r >> 5;
    const int lg  = (r >> 3) & 3;
    const int e   = r & 7;
    const int seg = 4 * mi + 2 * (lg >> 1) + (e >> 2);
    const int tap = 4 * (lg & 1) + (e & 3);

    float acc[4] = {0.0f, 0.0f, 0.0f, 0.0f};
    if (seg < SEGS && tap < KSZ) {
        int o = oc * WPB + seg * KSZ + tap;
        float bias = b2[o];
#pragma unroll
        for (int q = 0; q < 4; ++q) acc[q] = bias;
        const float* w2p = W2 + o;
#pragma unroll 8
        for (int j = 0; j < HIDDEN; ++j) {
            float w = w2p[(size_t)j * OUT_DIM];
#pragma unroll
            for (int q = 0; q < 4; ++q) acc[q] += hs[q][j] * w;
        }
    }
#pragma unroll
    for (int q = 0; q < 4; ++q)
        wq[(size_t)(b0 + q) * WQ_PER_B + op] = __float2bfloat16(acc[q]);
}

// ---------------- Kernel 2: grouped conv as implicit GEMM (MFMA) ----------------
// grid(112, 32), block(256) = 4 waves; block = one (b, oh); wave w = oc-tile w.
// XCD-chunked oh. Staging = 3 global_load_lds(16B) per wave from padded bf16 x
// (vertical OOB rows -> zpad). Compute identical to R8.
__global__ void __launch_bounds__(256, 6)
conv_kernel(const unsigned int* __restrict__ xbf,
            const unsigned int* __restrict__ zpad,
            const __hip_bfloat16* __restrict__ wq,
            float* __restrict__ out) {
    __shared__ unsigned int xs[XSROWS * XRW];     // 24 rows * 480 B = 11.52 KB

    const int xblk = blockIdx.x;
    const int oh = (xblk & 7) * 14 + (xblk >> 3);
    const int b  = blockIdx.y;
    const int tid = threadIdx.x;
    const int w  = tid >> 6;            // wave -> oc-tile
    const int l  = tid & 63;
    const int lr = l & 15;              // A row (oc) / B,D col (pixel)
    const int lg = l >> 4;              // k-group / D row group

    // ---- A-fragments (this wave's oc-tile) ----
    const unsigned short* wqb = (const unsigned short*)wq
        + ((size_t)b * OUT_CH + w * 16 + lr) * (SEGP * 8);
    short8 afr[6];
#pragma unroll
    for (int mi = 0; mi < 6; ++mi)
        afr[mi] = *(const short8*)(wqb + mi * 32 + lg * 8);

    // ---- stage 21 rows via global_load_lds: 2 rows (960B) per issue, 3 issues/wave ----
    const int halfl = l / 30;           // which of the 2 rows this lane feeds
    const int lc    = l - 30 * halfl;   // 16B chunk within row
#pragma unroll
    for (int i = 0; i < 3; ++i) {
        int d   = w + 4 * i;            // double-row 0..11
        int seg = 2 * d + halfl;        // 0..23
        const unsigned int* src = zpad;
        if (seg < SEGS) {
            int c  = seg / KSZ;
            int kh = seg - c * KSZ;
            int ih = oh * STRIDE + kh - PAD;
            if ((unsigned)ih < (unsigned)H_IN)
                src = xbf + ((size_t)(b * MAX_IN + c) * H_IN + ih) * XRW;
        }
        if (l < 60)
            __builtin_amdgcn_global_load_lds(
                (const __attribute__((address_space(1))) unsigned int*)(src + lc * 4),
                (__attribute__((address_space(3))) unsigned int*)(xs + d * 240),
                16, 0, 0);
    }
    __syncthreads();

    // ---- per-lane LDS u32 bases: 2 rows per mi, col = lr + 2*(lg&1) ----
    const int col = lr + 2 * (lg & 1);
    int ra[6], rb[6];
#pragma unroll
    for (int mi = 0; mi < 6; ++mi) {
        int sa = 4 * mi + 2 * (lg >> 1);
        int sb = sa + 1;
        ra[mi] = (sa < SEGS ? sa : 0) * XRW + col;   // clamped rows pair with 0-weights
        rb[mi] = (sb < SEGS ? sb : 0) * XRW + col;
    }

#pragma unroll
    for (int t = 0; t < 7; ++t) {
        const int tb = t * 16;
        floatx4 acc = {0.0f, 0.0f, 0.0f, 0.0f};
#pragma unroll
        for (int mi = 0; mi < 6; ++mi) {
            union { short8 s; unsigned int u[4]; } bu;
            const unsigned int* pa = xs + ra[mi] + tb;
            const unsigned int* pb = xs + rb[mi] + tb;
            bu.u[0] = pa[0];
            bu.u[1] = pa[1];
            bu.u[2] = pb[0];
            bu.u[3] = pb[1];
            acc = __builtin_amdgcn_mfma_f32_16x16x32_bf16(afr[mi], bu.s, acc, 0, 0, 0);
        }
        const int ow = tb + lr;
        float* op = out + (((size_t)b * OUT_CH + w * 16 + lg * 4) * H_OUT + oh) * W_OUT + ow;
#pragma unroll
        for (int r = 0; r < 4; ++r)
            op[(size_t)r * H_OUT * W_OUT] = acc[r];
    }
}

extern "C" void kernel_launch(void* const* d_in, const int* in_sizes, int n_in,
                              void* d_out, int out_size, void* d_ws, size_t ws_size,
                              hipStream_t stream) {
    const float* x    = (const float*)d_in[0];   // [32,3,224,224]
    const float* mask = (const float*)d_in[1];   // [32,3]
    const float* W1   = (const float*)d_in[2];   // [3,128]
    const float* b1   = (const float*)d_in[3];   // [128]
    const float* W2   = (const float*)d_in[4];   // [128,9408]
    const float* b2   = (const float*)d_in[5];   // [9408]
    float* out = (float*)d_out;

    // workspace: wq 768KB | xbf 10.32MB | zpad 480B   (ws >= ~390MB per harness fills)
    __hip_bfloat16* wq  = (__hip_bfloat16*)d_ws;
    unsigned int* xbf   = (unsigned int*)((char*)d_ws + 786432);
    unsigned int* zpad  = (unsigned int*)((char*)d_ws + 786432 + (size_t)B_SZ * MAX_IN * H_IN * XRW * 4);

    const int xprep_blocks = (B_SZ * MAX_IN * H_IN * XRW) / 256;   // 10080 exact
    xprep_kernel<<<dim3(xprep_blocks), dim3(256), 0, stream>>>(x, xbf, zpad);
    wgen_kernel<<<dim3(8, 48), dim3(256), 0, stream>>>(mask, W1, b1, W2, b2, wq);
    conv_kernel<<<dim3(112, B_SZ), dim3(256), 0, stream>>>(xbf, zpad, wq, out);
}

// Round 10
// 37.777 us; speedup vs baseline: 2.2323x; 1.1919x over previous
//
#include <hip/hip_runtime.h>
#include <hip/hip_bf16.h>

#define OUT_CH 64
#define KSZ 7
#define STRIDE 2
#define PAD 3
#define HIDDEN 128
#define MAX_IN 3
#define B_SZ 32
#define H_IN 224
#define W_IN 224
#define H_OUT 112
#define W_OUT 112
#define WPB 147                       // 3*7*7 taps per (b,oc)
#define OUT_DIM (OUT_CH * WPB)        // 9408
#define SEGS 21                       // 3 channels * 7 kh rows
#define SEGP 24                       // padded segment count (6 MFMAs * 4)
#define WQ_PER_B (OUT_CH * SEGP * 8)  // 12288 bf16 per batch row
#define XRW 120                       // u32 per x row (240 bf16, iw = j-3)
#define XSROWS 24                     // LDS rows (21 real + 3 scratch)
#define WGEN_BLOCKS 384               // 8 b-quartets * 48 o-chunks
#define XPREP_BLOCKS 10080            // 32*3*224*120/256

typedef __attribute__((ext_vector_type(8))) short short8;
typedef __attribute__((ext_vector_type(4))) float floatx4;

// ---------------- Kernel 0: fused prep (wgen blocks first, then xprep) ----------------
// wgen: wq[b][oc][mi][lg][e] bf16, seg = 4*mi + 2*(lg>>1) + (e>>2), tap = 4*(lg&1) + (e&3)
// xprep: xbf[(b*3+c)*224+ih][uw] u32 = bf16 pair (iw=2uw-3, 2uw-2), zero-padded; zpad row.
__global__ void prep_kernel(const float* __restrict__ x,
                            const float* __restrict__ mask,
                            const float* __restrict__ W1,
                            const float* __restrict__ b1,
                            const float* __restrict__ W2,
                            const float* __restrict__ b2,
                            __hip_bfloat16* __restrict__ wq,
                            unsigned int* __restrict__ xbf,
                            unsigned int* __restrict__ zpad) {
    __shared__ float hs[4][HIDDEN];
    const int tid = threadIdx.x;
    const int bid = blockIdx.x;

    if (bid < WGEN_BLOCKS) {
        // ---------------- weight generator ----------------
        const int gb    = bid / 48;          // 0..7  -> b-quartet
        const int chunk = bid - gb * 48;     // 0..47 -> 256-slot o-chunk
        const int b0 = gb * 4;

        for (int i = tid; i < 4 * HIDDEN; i += 256) {
            int q = i >> 7;
            int j = i & (HIDDEN - 1);
            float a = b1[j];
#pragma unroll
            for (int c = 0; c < MAX_IN; ++c)
                a += mask[(b0 + q) * MAX_IN + c] * W1[c * HIDDEN + j];
            hs[q][j] = fmaxf(a, 0.0f);
        }
        __syncthreads();

        const int op = chunk * 256 + tid;    // 0..12287
        const int oc  = op / 192;
        const int r   = op - oc * 192;       // [mi][lg][e]
        const int mi  = r >> 5;
        const int lg  = (r >> 3) & 3;
        const int e   = r & 7;
        const int seg = 4 * mi + 2 * (lg >> 1) + (e >> 2);
        const int tap = 4 * (lg & 1) + (e & 3);

        float acc[4] = {0.0f, 0.0f, 0.0f, 0.0f};
        if (seg < SEGS && tap < KSZ) {
            int o = oc * WPB + seg * KSZ + tap;
            float bias = b2[o];
#pragma unroll
            for (int q = 0; q < 4; ++q) acc[q] = bias;
            const float* w2p = W2 + o;
#pragma unroll 8
            for (int j = 0; j < HIDDEN; ++j) {
                float w = w2p[(size_t)j * OUT_DIM];
#pragma unroll
                for (int q = 0; q < 4; ++q) acc[q] += hs[q][j] * w;
            }
        }
#pragma unroll
        for (int q = 0; q < 4; ++q)
            wq[(size_t)(b0 + q) * WQ_PER_B + op] = __float2bfloat16(acc[q]);
    } else {
        // ---------------- x f32 -> padded bf16 rows ----------------
        const int xbid = bid - WGEN_BLOCKS;
        int s = xbid * 256 + tid;            // 0 .. 32*3*224*120-1 exact
        int r = s / XRW;
        int uw = s - r * XRW;
        const float* xr = x + (size_t)r * W_IN;
        int iw0 = 2 * uw - 3;
        float f0 = ((unsigned)iw0 < (unsigned)W_IN) ? xr[iw0] : 0.0f;
        float f1 = ((unsigned)(iw0 + 1) < (unsigned)W_IN) ? xr[iw0 + 1] : 0.0f;
        unsigned int lo = __bfloat16_as_ushort(__float2bfloat16(f0));
        unsigned int hi = __bfloat16_as_ushort(__float2bfloat16(f1));
        xbf[s] = lo | (hi << 16);
        if (xbid == 0 && tid < XRW) zpad[tid] = 0;
    }
}

// ---------------- Kernel 1: grouped conv as implicit GEMM (MFMA) ----------------
// grid(112, 32), block(256) = 4 waves; block = one (b, oh); wave w = oc-tile w.
// XCD-chunked oh. Staging = 3 global_load_lds(16B) per wave from padded bf16 x
// (vertical OOB rows -> zpad).
__global__ void __launch_bounds__(256, 6)
conv_kernel(const unsigned int* __restrict__ xbf,
            const unsigned int* __restrict__ zpad,
            const __hip_bfloat16* __restrict__ wq,
            float* __restrict__ out) {
    __shared__ unsigned int xs[XSROWS * XRW];     // 24 rows * 480 B = 11.52 KB

    const int xblk = blockIdx.x;
    const int oh = (xblk & 7) * 14 + (xblk >> 3);
    const int b  = blockIdx.y;
    const int tid = threadIdx.x;
    const int w  = tid >> 6;            // wave -> oc-tile
    const int l  = tid & 63;
    const int lr = l & 15;              // A row (oc) / B,D col (pixel)
    const int lg = l >> 4;              // k-group / D row group

    // ---- A-fragments (this wave's oc-tile) ----
    const unsigned short* wqb = (const unsigned short*)wq
        + ((size_t)b * OUT_CH + w * 16 + lr) * (SEGP * 8);
    short8 afr[6];
#pragma unroll
    for (int mi = 0; mi < 6; ++mi)
        afr[mi] = *(const short8*)(wqb + mi * 32 + lg * 8);

    // ---- stage 21 rows via global_load_lds: 2 rows (960B) per issue, 3 issues/wave ----
    const int halfl = l / 30;           // which of the 2 rows this lane feeds
    const int lc    = l - 30 * halfl;   // 16B chunk within row
#pragma unroll
    for (int i = 0; i < 3; ++i) {
        int d   = w + 4 * i;            // double-row 0..11
        int seg = 2 * d + halfl;        // 0..23
        const unsigned int* src = zpad;
        if (seg < SEGS) {
            int c  = seg / KSZ;
            int kh = seg - c * KSZ;
            int ih = oh * STRIDE + kh - PAD;
            if ((unsigned)ih < (unsigned)H_IN)
                src = xbf + ((size_t)(b * MAX_IN + c) * H_IN + ih) * XRW;
        }
        if (l < 60)
            __builtin_amdgcn_global_load_lds(
                (const __attribute__((address_space(1))) unsigned int*)(src + lc * 4),
                (__attribute__((address_space(3))) unsigned int*)(xs + d * 240),
                16, 0, 0);
    }
    __syncthreads();

    // ---- per-lane LDS u32 bases: 2 rows per mi, col = lr + 2*(lg&1) ----
    const int col = lr + 2 * (lg & 1);
    int ra[6], rb[6];
#pragma unroll
    for (int mi = 0; mi < 6; ++mi) {
        int sa = 4 * mi + 2 * (lg >> 1);
        int sb = sa + 1;
        ra[mi] = (sa < SEGS ? sa : 0) * XRW + col;   // clamped rows pair with 0-weights
        rb[mi] = (sb < SEGS ? sb : 0) * XRW + col;
    }

#pragma unroll
    for (int t = 0; t < 7; ++t) {
        const int tb = t * 16;
        floatx4 acc = {0.0f, 0.0f, 0.0f, 0.0f};
#pragma unroll
        for (int mi = 0; mi < 6; ++mi) {
            union { short8 s; unsigned int u[4]; } bu;
            const unsigned int* pa = xs + ra[mi] + tb;
            const unsigned int* pb = xs + rb[mi] + tb;
            bu.u[0] = pa[0];
            bu.u[1] = pa[1];
            bu.u[2] = pb[0];
            bu.u[3] = pb[1];
            acc = __builtin_amdgcn_mfma_f32_16x16x32_bf16(afr[mi], bu.s, acc, 0, 0, 0);
        }
        const int ow = tb + lr;
        float* op = out + (((size_t)b * OUT_CH + w * 16 + lg * 4) * H_OUT + oh) * W_OUT + ow;
#pragma unroll
        for (int r = 0; r < 4; ++r)
            op[(size_t)r * H_OUT * W_OUT] = acc[r];
    }
}

extern "C" void kernel_launch(void* const* d_in, const int* in_sizes, int n_in,
                              void* d_out, int out_size, void* d_ws, size_t ws_size,
                              hipStream_t stream) {
    const float* x    = (const float*)d_in[0];   // [32,3,224,224]
    const float* mask = (const float*)d_in[1];   // [32,3]
    const float* W1   = (const float*)d_in[2];   // [3,128]
    const float* b1   = (const float*)d_in[3];   // [128]
    const float* W2   = (const float*)d_in[4];   // [128,9408]
    const float* b2   = (const float*)d_in[5];   // [9408]
    float* out = (float*)d_out;

    // workspace: wq 768KB | xbf 10.32MB | zpad 480B
    __hip_bfloat16* wq  = (__hip_bfloat16*)d_ws;
    unsigned int* xbf   = (unsigned int*)((char*)d_ws + 786432);
    unsigned int* zpad  = (unsigned int*)((char*)d_ws + 786432 + (size_t)B_SZ * MAX_IN * H_IN * XRW * 4);

    prep_kernel<<<dim3(WGEN_BLOCKS + XPREP_BLOCKS), dim3(256), 0, stream>>>(
        x, mask, W1, b1, W2, b2, wq, xbf, zpad);
    conv_kernel<<<dim3(112, B_SZ), dim3(256), 0, stream>>>(xbf, zpad, wq, out);
}